// Round 1
// baseline (1065.768 us; speedup 1.0000x reference)
//
#include <hip/hip_runtime.h>

#define N_USER 100000
#define N_NODE 150000
#define N_EDGE 2400000
#define DIM 64
#define BPAIR 4096
#define NEG_SLOPE 0.01f

// ---------------- CSR build ----------------

__global__ void count_kernel(const int* __restrict__ rows, int* __restrict__ cnt) {
    int i = blockIdx.x * blockDim.x + threadIdx.x;
    if (i < N_EDGE) atomicAdd(&cnt[rows[i]], 1);
}

// 256-element block-wise inclusive scan; incl = row_ptr + 1
__global__ void scan1_kernel(const int* __restrict__ cnt, int* __restrict__ incl,
                             int* __restrict__ bsums) {
    __shared__ int s[256];
    int t = threadIdx.x;
    int i = blockIdx.x * 256 + t;
    s[t] = (i < N_NODE) ? cnt[i] : 0;
    __syncthreads();
    for (int off = 1; off < 256; off <<= 1) {
        int add = (t >= off) ? s[t - off] : 0;
        __syncthreads();
        s[t] += add;
        __syncthreads();
    }
    if (i < N_NODE) incl[i] = s[t];
    if (t == 255) bsums[blockIdx.x] = s[255];
}

__global__ void scan2_kernel(int* __restrict__ bsums, int nblk) {
    __shared__ int s[1024];
    int t = threadIdx.x;
    s[t] = (t < nblk) ? bsums[t] : 0;
    __syncthreads();
    for (int off = 1; off < 1024; off <<= 1) {
        int add = (t >= off) ? s[t - off] : 0;
        __syncthreads();
        s[t] += add;
        __syncthreads();
    }
    if (t < nblk) bsums[t] = s[t];
}

__global__ void scan3_kernel(int* __restrict__ row_ptr, const int* __restrict__ bsums) {
    int i = blockIdx.x * 256 + threadIdx.x;
    if (i == 0) row_ptr[0] = 0;
    if (i < N_NODE && blockIdx.x > 0) row_ptr[1 + i] += bsums[blockIdx.x - 1];
}

__global__ void scatter_kernel(const int* __restrict__ rows, const int* __restrict__ cols,
                               const float* __restrict__ vals, const int* __restrict__ row_ptr,
                               int* __restrict__ cursor, int* __restrict__ col_s,
                               float* __restrict__ val_s) {
    int i = blockIdx.x * blockDim.x + threadIdx.x;
    if (i < N_EDGE) {
        int r = rows[i];
        int p = row_ptr[r] + atomicAdd(&cursor[r], 1);
        col_s[p] = cols[i];
        val_s[p] = vals[i];
    }
}

// ---------------- fused SpMM + dense layer ----------------
// One wave per row: lane d owns feature dim d. Edge loop does coalesced
// 256B gathers of fin[col]; dense transform fused via per-wave LDS h1/h2
// (broadcast reads) and transposed+padded W tiles (conflict-free).
__global__ __launch_bounds__(256) void layer_kernel(
    const int* __restrict__ row_ptr, const int* __restrict__ col_s,
    const float* __restrict__ val_s, const float* __restrict__ fin,
    float* __restrict__ fout,
    const float* __restrict__ W1l, const float* __restrict__ b1l,
    const float* __restrict__ W2l, const float* __restrict__ b2l) {
    __shared__ float w1t[64][65];   // w1t[k][d] = W1l[d*64+k], pad 65 -> conflict-free
    __shared__ float w2t[64][65];
    __shared__ float h1s[4][64];
    __shared__ float h2s[4][64];
    int t = threadIdx.x;
    for (int idx = t; idx < 4096; idx += 256) {
        int d = idx >> 6, k = idx & 63;
        w1t[k][d] = W1l[idx];
        w2t[k][d] = W2l[idx];
    }
    __syncthreads();
    int wave = t >> 6, lane = t & 63;
    int gwave = (blockIdx.x * 256 + t) >> 6;
    int nwave = (gridDim.x * 256) >> 6;
    float bsum = b1l[lane] + b2l[lane];
    for (int r = gwave; r < N_NODE; r += nwave) {
        int e0 = row_ptr[r], e1 = row_ptr[r + 1];
        float acc = 0.f;
        int j = e0;
        for (; j + 3 < e1; j += 4) {           // unroll x4 for gather ILP
            int c0 = col_s[j], c1 = col_s[j + 1], c2 = col_s[j + 2], c3 = col_s[j + 3];
            float v0 = val_s[j], v1 = val_s[j + 1], v2 = val_s[j + 2], v3 = val_s[j + 3];
            acc += v0 * fin[(size_t)c0 * DIM + lane];
            acc += v1 * fin[(size_t)c1 * DIM + lane];
            acc += v2 * fin[(size_t)c2 * DIM + lane];
            acc += v3 * fin[(size_t)c3 * DIM + lane];
        }
        for (; j < e1; ++j)
            acc += val_s[j] * fin[(size_t)col_s[j] * DIM + lane];
        float f = fin[(size_t)r * DIM + lane];
        float h1 = acc + f;
        float h2 = acc * f;
        h1s[wave][lane] = h1;
        h2s[wave][lane] = h2;
        // wave-local LDS RAW: compiler inserts lgkmcnt wait; no barrier needed
        float o = bsum;
#pragma unroll 8
        for (int k = 0; k < 64; ++k) {
            o += w1t[k][lane] * h1s[wave][k] + w2t[k][lane] * h2s[wave][k];
        }
        o = (o > 0.f) ? o : NEG_SLOPE * o;
        fout[(size_t)r * DIM + lane] = o;
    }
}

// gather the 8192 selected rows (4096 users, 4096 items) of this layer's output
__global__ void gather_kernel(float* __restrict__ dst, const float* __restrict__ src,
                              const int* __restrict__ users, const int* __restrict__ items) {
    int t = threadIdx.x;
    int p = blockIdx.x * 4 + (t >> 6);
    int lane = t & 63;
    if (p < 2 * BPAIR) {
        int node = (p < BPAIR) ? users[p] : (N_USER + items[p - BPAIR]);
        dst[(size_t)p * DIM + lane] = src[(size_t)node * DIM + lane];
    }
}

__global__ void transpose_wt_kernel(const float* __restrict__ Wt, float* __restrict__ wtT) {
    int i = blockIdx.x * 256 + threadIdx.x;  // 64 blocks x 256 = 16384
    int d = i >> 8, k = i & 255;
    wtT[k * 64 + d] = Wt[i];
}

// one wave per pair: lane d computes pu[d], pv[d]; 64-lane shuffle reduce
__global__ __launch_bounds__(256) void score_kernel(
    const float* __restrict__ features, const float* __restrict__ sel,
    const int* __restrict__ users, const int* __restrict__ items,
    const float* __restrict__ wtT, const float* __restrict__ bt,
    float* __restrict__ out) {
    __shared__ float hu[4][256];
    __shared__ float hv[4][256];
    int t = threadIdx.x;
    int wave = t >> 6, lane = t & 63;
    int gwave = (blockIdx.x * 256 + t) >> 6;
    int nwave = (gridDim.x * 256) >> 6;
    float btv = bt[lane];
    for (int p = gwave; p < BPAIR; p += nwave) {
        int u = users[p];
        int v = N_USER + items[p];
        hu[wave][lane] = features[(size_t)u * DIM + lane];
        hv[wave][lane] = features[(size_t)v * DIM + lane];
        for (int l = 0; l < 3; ++l) {
            hu[wave][64 + l * 64 + lane] = sel[((size_t)l * 2 * BPAIR + p) * DIM + lane];
            hv[wave][64 + l * 64 + lane] = sel[((size_t)l * 2 * BPAIR + BPAIR + p) * DIM + lane];
        }
        float pu = btv, pv = btv;
#pragma unroll 4
        for (int k = 0; k < 256; ++k) {
            float w = wtT[k * 64 + lane];   // coalesced, L1/L2-resident 64KB
            pu += w * hu[wave][k];          // LDS broadcast
            pv += w * hv[wave][k];
        }
        float s = pu * pv;
        for (int m = 32; m >= 1; m >>= 1) s += __shfl_xor(s, m, 64);
        if (lane == 0) out[p] = s;
    }
}

extern "C" void kernel_launch(void* const* d_in, const int* in_sizes, int n_in,
                              void* d_out, int out_size, void* d_ws, size_t ws_size,
                              hipStream_t stream) {
    const float* features = (const float*)d_in[0];
    const int*   rows     = (const int*)d_in[1];
    const int*   cols     = (const int*)d_in[2];
    const float* vals     = (const float*)d_in[3];
    const int*   users    = (const int*)d_in[4];
    const int*   items    = (const int*)d_in[5];
    const float* W1       = (const float*)d_in[6];
    const float* b1       = (const float*)d_in[7];
    const float* W2       = (const float*)d_in[8];
    const float* b2       = (const float*)d_in[9];
    const float* Wt       = (const float*)d_in[10];
    const float* bt       = (const float*)d_in[11];
    float* out = (float*)d_out;

    char* ws = (char*)d_ws;
    size_t off = 0;
    auto alloc = [&](size_t bytes) -> void* {
        void* p = ws + off;
        off += (bytes + 255) & ~(size_t)255;
        return p;
    };
    int*   row_ptr = (int*)alloc((N_NODE + 1) * sizeof(int));
    int*   cnt     = (int*)alloc(N_NODE * sizeof(int));
    int*   cursor  = (int*)alloc(N_NODE * sizeof(int));
    int*   bsums   = (int*)alloc(4096);
    int*   col_s   = (int*)alloc(N_EDGE * sizeof(int));
    float* val_s   = (float*)alloc(N_EDGE * sizeof(float));
    float* f0      = (float*)alloc((size_t)N_NODE * DIM * sizeof(float));
    float* f1      = (float*)alloc((size_t)N_NODE * DIM * sizeof(float));
    float* sel     = (float*)alloc((size_t)3 * 2 * BPAIR * DIM * sizeof(float));
    float* wtT     = (float*)alloc(256 * 64 * sizeof(float));

    // cnt and cursor are contiguous padded regions; zero both
    hipMemsetAsync(cnt, 0, 2 * (((size_t)N_NODE * sizeof(int) + 255) & ~(size_t)255), stream);

    int eblocks = (N_EDGE + 255) / 256;
    int nblk = (N_NODE + 255) / 256;  // 586 <= 1024
    count_kernel<<<eblocks, 256, 0, stream>>>(rows, cnt);
    scan1_kernel<<<nblk, 256, 0, stream>>>(cnt, row_ptr + 1, bsums);
    scan2_kernel<<<1, 1024, 0, stream>>>(bsums, nblk);
    scan3_kernel<<<nblk, 256, 0, stream>>>(row_ptr, bsums);
    scatter_kernel<<<eblocks, 256, 0, stream>>>(rows, cols, vals, row_ptr, cursor, col_s, val_s);
    transpose_wt_kernel<<<64, 256, 0, stream>>>(Wt, wtT);

    const float* fin = features;
    float* fbuf[2] = {f0, f1};
    for (int l = 0; l < 3; ++l) {
        float* fout = fbuf[l & 1];
        layer_kernel<<<2048, 256, 0, stream>>>(row_ptr, col_s, val_s, fin, fout,
                                               W1 + (size_t)l * DIM * DIM, b1 + (size_t)l * DIM,
                                               W2 + (size_t)l * DIM * DIM, b2 + (size_t)l * DIM);
        gather_kernel<<<(2 * BPAIR) / 4, 256, 0, stream>>>(sel + (size_t)l * 2 * BPAIR * DIM,
                                                           fout, users, items);
        fin = fout;
    }
    score_kernel<<<256, 256, 0, stream>>>(features, sel, users, items, wtT, bt, out);
}